// Round 10
// baseline (39.480 us; speedup 1.0000x reference)
//
#include <hip/hip_runtime.h>
#include <math.h>

#define Bdim 64
#define Tdim 512
#define Sdim 400
#define Hdim 768
#define Ldim 9
#define PSTRIDE 12  // padded proj row stride (16B-aligned)

#define PROJ_BLOCKS 2048
#define ROWS_PER_BLK 16  // 2048 * 16 = 32768 = B*T physical rows

// ---------------------------------------------------------------------------
// DPP 64-lane sum (row_shr 1/2/4/8 + row_bcast 15/31), result in lane 63.
// Pure VALU, no DS pipe.
// ---------------------------------------------------------------------------
template <int CTRL>
__device__ __forceinline__ float dpp_add(float x) {
  int y = __builtin_amdgcn_update_dpp(0, __float_as_int(x), CTRL, 0xF, 0xF, false);
  return x + __int_as_float(y);
}
__device__ __forceinline__ float wave_sum63(float x) {
  x = dpp_add<0x111>(x);
  x = dpp_add<0x112>(x);
  x = dpp_add<0x114>(x);
  x = dpp_add<0x118>(x);
  x = dpp_add<0x142>(x);
  x = dpp_add<0x143>(x);
  return x;  // lane 63 = sum of all 64 lanes
}

// ---------------------------------------------------------------------------
// Kernel 1: streaming projection of VALID rows only.
// Each block owns 16 physical rows; the 16 attn bits are fetched once
// (ballot) and every load/compute step is guarded by its wave-uniform bit:
// pad rows cost zero bytes (saves ~25 MB vs R9's project-everything).
// Block = 192 threads = 3 waves; wave w computes logits {3w..3w+2} with a
// 36-float register W fragment (R5: bigger fragments silently rematerialize).
// No min-occupancy clamp: launch_bounds(192,4)'s 128-VGPR cap risked spilling
// the wf + ping-pong buffers (~120-130 VGPR).
// Block 0 zeroes the loss accumulators (ws is not re-poisoned).
// ---------------------------------------------------------------------------
__global__ __launch_bounds__(192) void proj_kernel(
    const float* __restrict__ enc, const float* __restrict__ W,
    const int* __restrict__ attn, float* __restrict__ proj,
    float* __restrict__ accum, unsigned* __restrict__ counter) {
  int tid = threadIdx.x;
  int lane = tid & 63;
  int w = tid >> 6;   // 0..2
  int l0 = w * 3;     // logit slice {l0, l0+1, l0+2}
  int base = blockIdx.x * ROWS_PER_BLK;

  if (blockIdx.x == 0) {
    if (tid < 2) accum[tid] = 0.0f;
    if (tid == 2) *counter = 0u;
  }

  // 16 validity bits for this block's rows (wave-uniform scalar mask)
  int mybit = attn[base + (lane & 15)];
  unsigned long long bal = __ballot(mybit != 0);
  unsigned mask = (unsigned)(bal & 0xFFFFu);
  if (mask == 0) return;

  // per-lane W fragment: h = 4*lane + 256*k + j (k<3, j<4), cols l0..l0+2
  float wf[3][4][3];
#pragma unroll
  for (int k = 0; k < 3; ++k)
#pragma unroll
    for (int j = 0; j < 4; ++j) {
      int h = 4 * lane + 256 * k + j;
#pragma unroll
      for (int c = 0; c < 3; ++c) wf[k][j][c] = W[(size_t)h * Ldim + l0 + c];
    }

  const float4* encf4 = (const float4*)enc;  // row p at p*(Hdim/4)

  float4 xa0, xa1, xa2, xb0, xb1, xb2;
#define VALID(I) ((I) < ROWS_PER_BLK && (mask >> (I)) & 1u)
#define LDROW(v0, v1, v2, IDX)                                             \
  if (VALID(IDX)) {                                                        \
    const float4* r_ = encf4 + (size_t)(base + (IDX)) * (Hdim / 4);        \
    v0 = r_[lane]; v1 = r_[lane + 64]; v2 = r_[lane + 128];                \
  }
#define PROCROW(v0, v1, v2, IDX)                                           \
  if (VALID(IDX)) {                                                        \
    float dd[3];                                                           \
    _Pragma("unroll") for (int c = 0; c < 3; ++c) {                        \
      dd[c] = v0.x * wf[0][0][c] + v0.y * wf[0][1][c] +                    \
              v0.z * wf[0][2][c] + v0.w * wf[0][3][c] +                    \
              v1.x * wf[1][0][c] + v1.y * wf[1][1][c] +                    \
              v1.z * wf[1][2][c] + v1.w * wf[1][3][c] +                    \
              v2.x * wf[2][0][c] + v2.y * wf[2][1][c] +                    \
              v2.z * wf[2][2][c] + v2.w * wf[2][3][c];                     \
      dd[c] = wave_sum63(dd[c]);                                           \
    }                                                                      \
    if (lane == 63) {                                                      \
      float* dst = proj + (size_t)(base + (IDX)) * PSTRIDE + l0;           \
      dst[0] = dd[0]; dst[1] = dd[1]; dst[2] = dd[2];                      \
    }                                                                      \
  }

  LDROW(xa0, xa1, xa2, 0)
  LDROW(xb0, xb1, xb2, 1)
#pragma unroll
  for (int i = 0; i < ROWS_PER_BLK; i += 2) {
    PROCROW(xa0, xa1, xa2, i)
    LDROW(xa0, xa1, xa2, i + 2)
    PROCROW(xb0, xb1, xb2, i + 1)
    LDROW(xb0, xb1, xb2, i + 3)
  }
#undef VALID
#undef LDROW
#undef PROCROW
}

// ---------------------------------------------------------------------------
// Kernel 2: 4 blocks per batch row (256 blocks x 512 threads).
//  phase A: both scans in LDS (each block redoes them -- cheap, keeps
//           everything local; no global index buffers)
//  phase B: this block's 100 words: mean of token proj rows, +bias,
//           argmax -> out, NLL partial
//  phase C: block reduce; 256 block-atomics; last block finalizes loss.
// ---------------------------------------------------------------------------
__global__ __launch_bounds__(Tdim) void rowword_kernel(
    const float* __restrict__ proj, const float* __restrict__ bias,
    const int* __restrict__ attn, const int* __restrict__ ids_lens,
    const int* __restrict__ label_ids, float* __restrict__ out,
    float* __restrict__ accum, unsigned* __restrict__ counter) {
  int b = blockIdx.x >> 2;          // batch row
  int part = blockIdx.x & 3;        // word quarter: words part*100..+99
  int tid = threadIdx.x;
  int lane = tid & 63, wid = tid >> 6;
  __shared__ int p2t[Tdim];
  __shared__ int wst[Sdim];
  __shared__ int wsum[8];
  __shared__ int totsm;
  __shared__ float ssm[8], csm[8];

  // ---- scan 1: attention mask -> p2t (LDS), nvalid ----
  int m = attn[b * Tdim + tid];
  int x = m;
#pragma unroll
  for (int off = 1; off < 64; off <<= 1) {
    int v = __shfl_up(x, off, 64);
    if (lane >= off) x += v;
  }
  if (lane == 63) wsum[wid] = x;
  __syncthreads();
  if (tid < 8) {
    int s = wsum[tid], y = s;
#pragma unroll
    for (int off = 1; off < 8; off <<= 1) {
      int v = __shfl_up(y, off, 64);
      if (tid >= off) y += v;
    }
    wsum[tid] = y - s;
    if (tid == 7) totsm = y;
  }
  __syncthreads();
  x += wsum[wid];
  if (m) p2t[x - 1] = tid;  // q-th valid token -> physical position tid
  int nv_local = totsm;
  __syncthreads();  // p2t written; wsum reusable

  // ---- scan 2: ids_lens -> wstart (LDS) ----
  int len = (tid < Sdim) ? ids_lens[b * Sdim + tid] : 0;
  int x2 = len;
#pragma unroll
  for (int off = 1; off < 64; off <<= 1) {
    int v = __shfl_up(x2, off, 64);
    if (lane >= off) x2 += v;
  }
  if (lane == 63) wsum[wid] = x2;
  __syncthreads();
  if (tid < 8) {
    int s = wsum[tid], y = s;
#pragma unroll
    for (int off = 1; off < 8; off <<= 1) {
      int v = __shfl_up(y, off, 64);
      if (tid >= off) y += v;
    }
    wsum[tid] = y - s;
  }
  __syncthreads();
  x2 += wsum[wid];
  if (tid < Sdim) wst[tid] = x2 - len;  // exclusive prefix
  __syncthreads();

  // ---- phase B: 100 words of this quarter ----
  float nll = 0.0f, cnt = 0.0f;
  int s_word = part * 100 + tid;  // tid < 100 active
  if (tid < 100) {
    int bs = b * Sdim + s_word;
    int wlen = ids_lens[bs];
    float sum[Ldim];
#pragma unroll
    for (int l = 0; l < Ldim; ++l) sum[l] = 0.0f;
    if (wlen > 0) {
      int start = wst[s_word];
      for (int j = 0; j < wlen; ++j) {
        int q = start + j;
        if (q >= nv_local) break;
        const float* pr = proj + ((size_t)(b << 9) + p2t[q]) * PSTRIDE;
        const float4* pr4 = (const float4*)pr;
        float4 r0 = pr4[0], r1 = pr4[1];
        float r8 = pr[8];
        sum[0] += r0.x; sum[1] += r0.y; sum[2] += r0.z; sum[3] += r0.w;
        sum[4] += r1.x; sum[5] += r1.y; sum[6] += r1.z; sum[7] += r1.w;
        sum[8] += r8;
      }
    }
    float inv = (wlen > 0) ? 1.0f / (float)wlen : 0.0f;
    float lg[Ldim];
#pragma unroll
    for (int l = 0; l < Ldim; ++l) lg[l] = sum[l] * inv + bias[l];

    int amax = 0;
    float mx = lg[0];
#pragma unroll
    for (int l = 1; l < Ldim; ++l)
      if (lg[l] > mx) { mx = lg[l]; amax = l; }
    out[1 + bs] = (float)amax;

    if (wlen > 0) {
      float se = 0.0f;
#pragma unroll
      for (int l = 0; l < Ldim; ++l) se += expf(lg[l] - mx);
      float lse = mx + logf(se);
      int lab = label_ids[bs];
      float ll = lg[0];
#pragma unroll
      for (int l = 1; l < Ldim; ++l) ll = (lab == l) ? lg[l] : ll;
      nll = lse - ll;
      cnt = 1.0f;
    }
  }

  // ---- phase C: block reduce + finalize ----
#pragma unroll
  for (int off = 32; off > 0; off >>= 1) {
    nll += __shfl_down(nll, off, 64);
    cnt += __shfl_down(cnt, off, 64);
  }
  if (lane == 0) { ssm[wid] = nll; csm[wid] = cnt; }
  __syncthreads();
  if (tid == 0) {
    float S = 0.f, C = 0.f;
#pragma unroll
    for (int k = 0; k < 8; ++k) { S += ssm[k]; C += csm[k]; }
    atomicAdd(&accum[0], S);
    atomicAdd(&accum[1], C);
    __threadfence();
    unsigned prev = atomicAdd(counter, 1u);
    if (prev == gridDim.x - 1) {
      __threadfence();
      float Sf = atomicAdd(&accum[0], 0.0f);
      float Cf = atomicAdd(&accum[1], 0.0f);
      out[0] = Sf / Cf;
    }
  }
}

extern "C" void kernel_launch(void* const* d_in, const int* in_sizes, int n_in,
                              void* d_out, int out_size, void* d_ws, size_t ws_size,
                              hipStream_t stream) {
  const float* enc     = (const float*)d_in[0];  // [B,T,H] f32
  const float* W       = (const float*)d_in[1];  // [H,L]   f32
  const float* bias    = (const float*)d_in[2];  // [L]     f32
  const int* attn      = (const int*)d_in[3];    // [B,T]   i32
  const int* ids_lens  = (const int*)d_in[4];    // [B,S]   i32
  const int* label_ids = (const int*)d_in[5];    // [B,S]   i32
  // d_in[6] label_mask is recomputed from ids_lens>0

  float* out = (float*)d_out;  // [1 + B*S]: loss, then argmax as float

  char* ws = (char*)d_ws;
  size_t off0 = 0;
  float* accum      = (float*)(ws + off0);    off0 += 128;
  unsigned* counter = (unsigned*)(ws + off0); off0 += 128;
  float* proj       = (float*)(ws + off0);    off0 += (size_t)Bdim * Tdim * PSTRIDE * sizeof(float);

  proj_kernel<<<PROJ_BLOCKS, 192, 0, stream>>>(enc, W, attn, proj, accum, counter);
  rowword_kernel<<<Bdim * 4, Tdim, 0, stream>>>(proj, bias, attn, ids_lens,
                                                label_ids, out, accum, counter);
}